// Round 1
// baseline (1014.840 us; speedup 1.0000x reference)
//
#include <hip/hip_runtime.h>
#include <math.h>

#define HD 128
#define WDIM 128
#define BB 4
#define ICAPS 4
#define IDIMS 16
#define CINTOT 64
#define OCAP 8
#define ODIM 32
#define KS 5
#define PADK 2
#define TILE 32
#define HALO 36       // TILE + 2*PADK
#define CHUNK 4       // cin per LDS stage

__global__ __launch_bounds__(256)
void caps_conv_squash(const float* __restrict__ u,
                      const float* __restrict__ Wt,
                      const float* __restrict__ bias,
                      float* __restrict__ out) {
    __shared__ float su[CHUNK][HALO][HALO + 1];   // padded row stride 37
    __shared__ float sw[CHUNK][KS * KS][ODIM];
    __shared__ float bs[ODIM];

    const int tid = threadIdx.x;
    const int tileIdx = blockIdx.x;          // 0..15 (4x4 tiles of 32x32)
    const int oc = blockIdx.y;               // 0..7
    const int b  = blockIdx.z;               // 0..3
    const int tileY = (tileIdx >> 2) * TILE;
    const int tileX = (tileIdx & 3) * TILE;

    // summed bias over in-capsules for this oc
    if (tid < ODIM) {
        float s = 0.f;
        #pragma unroll
        for (int ic = 0; ic < ICAPS; ++ic)
            s += bias[ic * (OCAP * ODIM) + oc * ODIM + tid];
        bs[tid] = s;
    }

    const int tx = tid & 15;
    const int ty = tid >> 4;                 // 0..15

    float acc[4][ODIM];
    #pragma unroll
    for (int p = 0; p < 4; ++p)
        #pragma unroll
        for (int o = 0; o < ODIM; ++o) acc[p][o] = 0.f;

    const int oy = tileY - PADK;
    const int ox = tileX - PADK;

    for (int c0 = 0; c0 < CINTOT; c0 += CHUNK) {
        __syncthreads();
        // ---- stage u halo: CHUNK x 36 x 36 (zero-pad outside image) ----
        for (int i = tid; i < CHUNK * HALO * HALO; i += 256) {
            int c = i / (HALO * HALO);
            int rem = i - c * (HALO * HALO);
            int y = rem / HALO;
            int x = rem - y * HALO;
            int gy = oy + y, gx = ox + x;
            float v = 0.f;
            if ((unsigned)gy < (unsigned)HD && (unsigned)gx < (unsigned)WDIM)
                v = u[(((size_t)b * CINTOT + (c0 + c)) * HD + gy) * WDIM + gx];
            su[c][y][x] = v;
        }
        // ---- stage weights: CHUNK x 25 x 32 ----
        for (int i = tid; i < CHUNK * KS * KS * ODIM; i += 256) {
            int c = i / (KS * KS * ODIM);
            int rem = i - c * (KS * KS * ODIM);
            int k = rem / ODIM;
            int od = rem - k * ODIM;
            int cin = c0 + c;
            int ic = cin >> 4;
            int id = cin & 15;
            int o = oc * ODIM + od;
            sw[c][k][od] =
                Wt[(((size_t)ic * (OCAP * ODIM) + o) * IDIMS + id) * (KS * KS) + k];
        }
        __syncthreads();

        // ---- compute: each thread does 4 pixels x 32 od ----
        #pragma unroll 1
        for (int c = 0; c < CHUNK; ++c) {
            #pragma unroll 1
            for (int kh = 0; kh < KS; ++kh) {
                #pragma unroll
                for (int kw = 0; kw < KS; ++kw) {
                    float u00 = su[c][2 * ty + kh    ][tx + kw     ];
                    float u01 = su[c][2 * ty + kh    ][tx + kw + 16];
                    float u10 = su[c][2 * ty + kh + 1][tx + kw     ];
                    float u11 = su[c][2 * ty + kh + 1][tx + kw + 16];
                    const float4* w4 = (const float4*)&sw[c][kh * KS + kw][0];
                    #pragma unroll
                    for (int j = 0; j < 8; ++j) {
                        float4 wv = w4[j];
                        acc[0][4 * j + 0] += u00 * wv.x;
                        acc[0][4 * j + 1] += u00 * wv.y;
                        acc[0][4 * j + 2] += u00 * wv.z;
                        acc[0][4 * j + 3] += u00 * wv.w;
                        acc[1][4 * j + 0] += u01 * wv.x;
                        acc[1][4 * j + 1] += u01 * wv.y;
                        acc[1][4 * j + 2] += u01 * wv.z;
                        acc[1][4 * j + 3] += u01 * wv.w;
                        acc[2][4 * j + 0] += u10 * wv.x;
                        acc[2][4 * j + 1] += u10 * wv.y;
                        acc[2][4 * j + 2] += u10 * wv.z;
                        acc[2][4 * j + 3] += u10 * wv.w;
                        acc[3][4 * j + 0] += u11 * wv.x;
                        acc[3][4 * j + 1] += u11 * wv.y;
                        acc[3][4 * j + 2] += u11 * wv.z;
                        acc[3][4 * j + 3] += u11 * wv.w;
                    }
                }
            }
        }
    }

    // ---- epilogue: r-scale + bias + squash + transposed store ----
    #pragma unroll
    for (int dy = 0; dy < 2; ++dy) {
        int h = tileY + 2 * ty + dy;
        int rows = min(h + PADK, HD - 1) - max(h - PADK, 0) + 1;
        #pragma unroll
        for (int dx = 0; dx < 2; ++dx) {
            int w = tileX + tx + 16 * dx;
            int cols = min(w + PADK, WDIM - 1) - max(w - PADK, 0) + 1;
            float r = 1.0f / (8.0f * (float)(rows * cols));
            int p = dy * 2 + dx;  // matches acc ordering: u00,u01,u10,u11
            // note: p index mapping — acc[0]=(dy0,dx0), acc[1]=(dy0,dx1),
            //       acc[2]=(dy1,dx0), acc[3]=(dy1,dx1)
            float pv[ODIM];
            float sq = 0.f;
            #pragma unroll
            for (int o = 0; o < ODIM; ++o) {
                float v = (acc[p][o] + bs[o]) * r;
                pv[o] = v;
                sq += v * v;
            }
            float scale = sq / ((1.0f + sq) * sqrtf(sq + 1e-9f));
            float* op = out + (((size_t)(b * OCAP + oc) * ODIM) * HD + h) * WDIM + w;
            #pragma unroll
            for (int o = 0; o < ODIM; ++o)
                op[(size_t)o * HD * WDIM] = pv[o] * scale;
        }
    }
}

extern "C" void kernel_launch(void* const* d_in, const int* in_sizes, int n_in,
                              void* d_out, int out_size, void* d_ws, size_t ws_size,
                              hipStream_t stream) {
    const float* u    = (const float*)d_in[0];
    const float* Wt   = (const float*)d_in[1];
    const float* bias = (const float*)d_in[2];
    float* out = (float*)d_out;

    dim3 grid(16, OCAP, BB);   // 16 tiles of 32x32, 8 out-capsules, 4 batch
    dim3 block(256);
    caps_conv_squash<<<grid, block, 0, stream>>>(u, Wt, bias, out);
}

// Round 2
// 91.840 us; speedup vs baseline: 11.0501x; 11.0501x over previous
//
#include <hip/hip_runtime.h>
#include <math.h>

typedef __attribute__((ext_vector_type(8))) __bf16 b16x8;
typedef __attribute__((ext_vector_type(4))) float f32x4;

#define GLDS(gp, lp) __builtin_amdgcn_global_load_lds(                         \
    (const __attribute__((address_space(1))) unsigned int*)(gp),               \
    (__attribute__((address_space(3))) unsigned int*)(lp), 16, 0, 0)

__device__ __forceinline__ unsigned short f2bf(float x) {
    unsigned int v = __float_as_uint(x);
    v += 0x7fffu + ((v >> 16) & 1u);
    return (unsigned short)(v >> 16);
}

// ---------------- repack kernel ----------------
// ws layout: [0, 819200): weights bf16
//   idx = ((half*25 + tap)*256 + o)*32 + cgp*8 + j   (ushort index)
//   stored cin = half*32 + (cgp ^ ((o>>1)&3))*8 + j   (XOR swizzle for LDS banks)
// [819200, 820224): bias_sum fp32 [256]
__global__ __launch_bounds__(256) void repack_w(
    const float* __restrict__ Wt, const float* __restrict__ bias,
    unsigned short* __restrict__ wsw, float* __restrict__ wsb) {
    int idx = blockIdx.x * 256 + threadIdx.x;
    if (idx < 409600) {
        int j    = idx & 7;
        int cgp  = (idx >> 3) & 3;
        int o    = (idx >> 5) & 255;
        int it2  = idx >> 13;          // 0..49
        int tap  = it2 % 25;
        int half = it2 / 25;
        int cg   = cgp ^ ((o >> 1) & 3);
        int cin  = half * 32 + cg * 8 + j;
        int ic = cin >> 4, id = cin & 15;
        float w = Wt[((size_t)(ic * 256 + o) * 16 + id) * 25 + tap];
        wsw[idx] = f2bf(w);
    } else if (idx < 409856) {
        int o = idx - 409600;
        float s = 0.f;
        for (int ic = 0; ic < 4; ++ic) s += bias[ic * 256 + o];
        wsb[o] = s;
    }
}

// ---------------- main kernel ----------------
// Block: one 16x16 spatial tile x all 256 outputs, 512 threads (8 waves).
// Wave tile: 128 pixels x 64 outputs = 8 pixfrags x 4 ofrags (16x16x32 MFMA).
// K loop: 2 cin-halves x 25 taps; weights double-buffered via global_load_lds.
__global__ __launch_bounds__(512, 2) void caps_mfma(
    const float* __restrict__ u, const unsigned short* __restrict__ wsw,
    const float* __restrict__ wsb, float* __restrict__ out) {

    __shared__ __align__(16) unsigned short su_sh[12800];     // [hy20][hx20][cgp4][j8]
    __shared__ __align__(16) unsigned short sw_sh[2][8192];   // [o256][cgp4][j8]

    const int tid  = threadIdx.x;
    const int lane = tid & 63;
    const int wid  = tid >> 6;
    const int wm   = wid >> 2;      // 0..1  pixel-row-group
    const int wn   = wid & 3;       // 0..3  output-col-group
    const int col  = lane & 15;
    const int cg   = lane >> 4;     // 0..3  cin-group (and x-group in C layout)
    const int ybase = wm * 8;
    const int obase = wn * 64;

    const int bx  = blockIdx.x;     // 0..63
    const int b   = blockIdx.y;     // 0..3
    const int ty0 = (bx >> 3) * 16;
    const int tx0 = (bx & 7) * 16;

    // B-frag element offsets (ushorts) within one weight buffer
    int b_elem[4];
    #pragma unroll
    for (int fr = 0; fr < 4; ++fr) {
        int o = obase + fr * 16 + col;
        int cgp = cg ^ ((o >> 1) & 3);
        b_elem[fr] = o * 32 + cgp * 8;
    }

    f32x4 acc[8][4];
    #pragma unroll
    for (int f = 0; f < 8; ++f)
        #pragma unroll
        for (int fr = 0; fr < 4; ++fr) acc[f][fr] = (f32x4)0.f;

    auto stage_u = [&](int half) {
        const float* up = u + ((size_t)b * 64 + half * 32) * 16384;
        #pragma unroll 1
        for (int i = tid; i < 12800; i += 512) {
            int c = i / 400;                    // cin local 0..31
            int s = i - c * 400;
            int hy = s / 20, hx = s - hy * 20;  // halo coords 0..19
            int gy = ty0 - 2 + hy, gx = tx0 - 2 + hx;
            float v = 0.f;
            if ((unsigned)gy < 128u && (unsigned)gx < 128u)
                v = up[(size_t)c * 16384 + gy * 128 + gx];
            int cgp = (c >> 3) ^ ((hx >> 1) & 3);
            su_sh[(hy * 20 + hx) * 32 + cgp * 8 + (c & 7)] = f2bf(v);
        }
    };

    auto stage_w = [&](int it2, int bufI) {
        const char* src = ((const char*)wsw) + (size_t)it2 * 16384 + wid * 2048 + lane * 16;
        char* dst = ((char*)sw_sh) + bufI * 16384 + wid * 2048;   // wave-uniform dest
        GLDS(src, dst);
        GLDS(src + 1024, dst + 1024);
    };

    stage_u(0);
    stage_w(0, 0);
    __syncthreads();

    int buf = 0;
    #pragma unroll 1
    for (int half = 0; half < 2; ++half) {
        #pragma unroll 1
        for (int tap = 0; tap < 25; ++tap) {
            int it2 = half * 25 + tap;
            if (it2 + 1 < 50) stage_w(it2 + 1, buf ^ 1);
            int kh = tap / 5;
            int kw = tap - kh * 5;

            const unsigned short* swb = sw_sh[buf];
            b16x8 bfr[4];
            #pragma unroll
            for (int fr = 0; fr < 4; ++fr)
                bfr[fr] = *reinterpret_cast<const b16x8*>(swb + b_elem[fr]);

            int hx = col + kw;
            int coff = hx * 32 + ((cg ^ ((hx >> 1) & 3)) * 8);
            #pragma unroll
            for (int f = 0; f < 8; ++f) {
                int hy = ybase + f + kh;
                const b16x8 afr =
                    *reinterpret_cast<const b16x8*>(su_sh + hy * 640 + coff);
                #pragma unroll
                for (int fr = 0; fr < 4; ++fr)
                    acc[f][fr] = __builtin_amdgcn_mfma_f32_16x16x32_bf16(
                        afr, bfr[fr], acc[f][fr], 0, 0, 0);
            }

            if (it2 == 24) { __syncthreads(); stage_u(1); }
            __syncthreads();
            buf ^= 1;
        }
    }

    // ---------------- epilogue: bias + r-scale + squash + transposed store ----
    float bsv[4];
    #pragma unroll
    for (int fr = 0; fr < 4; ++fr) bsv[fr] = wsb[obase + fr * 16 + col];

    const int xg = lane >> 4;   // x-group in C layout
    #pragma unroll
    for (int f = 0; f < 8; ++f) {
        int h = ty0 + ybase + f;
        int rows = min(h + 2, 127) - max(h - 2, 0) + 1;
        #pragma unroll
        for (int p = 0; p < 2; ++p) {
            int oc = wn * 2 + p;
            float pv0[4], pv1[4], ss[4];
            #pragma unroll
            for (int r = 0; r < 4; ++r) {
                int w = tx0 + xg * 4 + r;
                int colsv = min(w + 2, 127) - max(w - 2, 0) + 1;
                float rs = 1.0f / (8.0f * (float)(rows * colsv));
                float p0 = (acc[f][2 * p][r] + bsv[2 * p]) * rs;
                float p1 = (acc[f][2 * p + 1][r] + bsv[2 * p + 1]) * rs;
                pv0[r] = p0; pv1[r] = p1;
                ss[r] = p0 * p0 + p1 * p1;
            }
            #pragma unroll
            for (int r = 0; r < 4; ++r) {
                float s = ss[r];
                s += __shfl_xor(s, 1);
                s += __shfl_xor(s, 2);
                s += __shfl_xor(s, 4);
                s += __shfl_xor(s, 8);
                float scale = s / ((1.0f + s) * sqrtf(s + 1e-9f));
                int w = tx0 + xg * 4 + r;
                size_t base0 = ((size_t)((b * 8 + oc) * 32) + col) * 16384
                               + (size_t)h * 128 + w;
                out[base0] = pv0[r] * scale;
                out[base0 + (size_t)16 * 16384] = pv1[r] * scale;
            }
        }
    }
}

extern "C" void kernel_launch(void* const* d_in, const int* in_sizes, int n_in,
                              void* d_out, int out_size, void* d_ws, size_t ws_size,
                              hipStream_t stream) {
    const float* u    = (const float*)d_in[0];
    const float* Wt   = (const float*)d_in[1];
    const float* bias = (const float*)d_in[2];
    unsigned short* wsw = (unsigned short*)d_ws;
    float* wsb = (float*)((char*)d_ws + 819200);

    repack_w<<<1601, 256, 0, stream>>>(Wt, bias, wsw, wsb);
    caps_mfma<<<dim3(64, 4), 512, 0, stream>>>(u, wsw, wsb, (float*)d_out);
}

// Round 3
// 78.301 us; speedup vs baseline: 12.9607x; 1.1729x over previous
//
#include <hip/hip_runtime.h>
#include <math.h>

typedef __attribute__((ext_vector_type(8))) __bf16 b16x8;
typedef __attribute__((ext_vector_type(4))) float f32x4;

#define GLDS(gp, lp) __builtin_amdgcn_global_load_lds(                         \
    (const __attribute__((address_space(1))) unsigned int*)(gp),               \
    (__attribute__((address_space(3))) unsigned int*)(lp), 16, 0, 0)

#define WAIT_VM2()   asm volatile("s_waitcnt vmcnt(2)" ::: "memory")
#define WAIT_LGKM0() asm volatile("s_waitcnt lgkmcnt(0)" ::: "memory")
#define SCHEDB()     __builtin_amdgcn_sched_barrier(0)
#define BAR()        __builtin_amdgcn_s_barrier()

__device__ __forceinline__ unsigned short f2bf(float x) {
    unsigned int v = __float_as_uint(x);
    v += 0x7fffu + ((v >> 16) & 1u);
    return (unsigned short)(v >> 16);
}

// ---------------- repack kernel ----------------
// ws layout: [0, 819200): weights bf16
//   idx = ((half*25 + tap)*256 + o)*32 + cgp*8 + j   (ushort index)
//   stored cin = half*32 + (cgp ^ ((o>>1)&3))*8 + j   (XOR swizzle for LDS banks)
// [819200, 820224): bias_sum fp32 [256]
__global__ __launch_bounds__(256) void repack_w(
    const float* __restrict__ Wt, const float* __restrict__ bias,
    unsigned short* __restrict__ wsw, float* __restrict__ wsb) {
    int idx = blockIdx.x * 256 + threadIdx.x;
    if (idx < 409600) {
        int j    = idx & 7;
        int cgp  = (idx >> 3) & 3;
        int o    = (idx >> 5) & 255;
        int it2  = idx >> 13;          // 0..49
        int tap  = it2 % 25;
        int half = it2 / 25;
        int cg   = cgp ^ ((o >> 1) & 3);
        int cin  = half * 32 + cg * 8 + j;
        int ic = cin >> 4, id = cin & 15;
        float w = Wt[((size_t)(ic * 256 + o) * 16 + id) * 25 + tap];
        wsw[idx] = f2bf(w);
    } else if (idx < 409856) {
        int o = idx - 409600;
        float s = 0.f;
        for (int ic = 0; ic < 4; ++ic) s += bias[ic * 256 + o];
        wsb[o] = s;
    }
}

// ---------------- main kernel ----------------
// Block: one 16x16 spatial tile x all 256 outputs, 512 threads (8 waves).
// Wave tile: 128 pixels x 64 outputs = 8 pixfrags x 4 ofrags (16x16x32 MFMA).
// K loop: 2 cin-halves x 25 taps. Weights triple-buffered (prefetch depth 2)
// via global_load_lds; per tap = 2 phases of 16 MFMA with raw s_barrier and
// counted vmcnt(2) (never drained to 0 in the main loop).
__global__ __launch_bounds__(512, 2) void caps_mfma(
    const float* __restrict__ u, const unsigned short* __restrict__ wsw,
    const float* __restrict__ wsb, float* __restrict__ out) {

    __shared__ __align__(16) unsigned short su_sh[12800];       // [hy20][hx20][cgp4][j8]
    __shared__ __align__(16) unsigned short sw_sh[3][8192];     // 3 x [o256][cgp4][j8]

    const int tid  = threadIdx.x;
    const int lane = tid & 63;
    const int wid  = tid >> 6;
    const int wm   = wid >> 2;      // 0..1  pixel-row-group
    const int wn   = wid & 3;       // 0..3  output-col-group
    const int col  = lane & 15;
    const int cg   = lane >> 4;     // 0..3  cin-group (and x-group in C layout)
    const int ybase = wm * 8;
    const int obase = wn * 64;

    const int bx  = blockIdx.x;     // 0..63
    const int b   = blockIdx.y;     // 0..3
    const int ty0 = (bx >> 3) * 16;
    const int tx0 = (bx & 7) * 16;

    // B-frag element offsets (ushorts) within one weight buffer
    int b_elem[4];
    #pragma unroll
    for (int fr = 0; fr < 4; ++fr) {
        int o = obase + fr * 16 + col;
        int cgp = cg ^ ((o >> 1) & 3);
        b_elem[fr] = o * 32 + cgp * 8;
    }

    // A-frag column offsets per kw (ushort index within a row cell)
    int coffs[5];
    #pragma unroll
    for (int kw = 0; kw < 5; ++kw) {
        int hx = col + kw;
        coffs[kw] = hx * 32 + ((cg ^ ((hx >> 1) & 3)) * 8);
    }

    f32x4 acc[8][4];
    #pragma unroll
    for (int f = 0; f < 8; ++f)
        #pragma unroll
        for (int fr = 0; fr < 4; ++fr) acc[f][fr] = (f32x4)0.f;

    auto stage_u = [&](int half) {
        const float* up = u + ((size_t)b * 64 + half * 32) * 16384;
        #pragma unroll 1
        for (int i = tid; i < 12800; i += 512) {
            int c = i / 400;                    // cin local 0..31
            int s = i - c * 400;
            int hy = s / 20, hx = s - hy * 20;  // halo coords 0..19
            int gy = ty0 - 2 + hy, gx = tx0 - 2 + hx;
            float v = 0.f;
            if ((unsigned)gy < 128u && (unsigned)gx < 128u)
                v = up[(size_t)c * 16384 + gy * 128 + gx];
            int cgp = (c >> 3) ^ ((hx >> 1) & 3);
            su_sh[(hy * 20 + hx) * 32 + cgp * 8 + (c & 7)] = f2bf(v);
        }
    };

    const char* wbase = ((const char*)wsw) + wid * 2048 + lane * 16;

    // prologue: stage u half 0 and weight taps 0,1
    stage_u(0);
    {
        char* dst0 = ((char*)sw_sh) + 0 * 16384 + wid * 2048;
        GLDS(wbase, dst0);
        GLDS(wbase + 1024, dst0 + 1024);
        char* dst1 = ((char*)sw_sh) + 1 * 16384 + wid * 2048;
        GLDS(wbase + 16384, dst1);
        GLDS(wbase + 16384 + 1024, dst1 + 1024);
    }
    __syncthreads();

    int bufR = 0, bufW = 2;
    #pragma unroll 1
    for (int half = 0; half < 2; ++half) {
        #pragma unroll 1
        for (int kh = 0; kh < 5; ++kh) {
            const int rowb = (ybase + kh) * 640;
            #pragma unroll
            for (int kw = 0; kw < 5; ++kw) {
                const int it2 = half * 25 + kh * 5 + kw;
                int itn = it2 + 2; if (itn > 49) itn = 49;   // clamped prefetch src
                const char* src = wbase + (size_t)itn * 16384;
                char* dst = ((char*)sw_sh) + bufW * 16384 + wid * 2048;
                const unsigned short* swb = sw_sh[bufR];
                const int coff = coffs[kw];

                // ================= phase A =================
                b16x8 bfr[4];
                #pragma unroll
                for (int fr = 0; fr < 4; ++fr)
                    bfr[fr] = *reinterpret_cast<const b16x8*>(swb + b_elem[fr]);
                b16x8 afA[4];
                #pragma unroll
                for (int f = 0; f < 4; ++f)
                    afA[f] = *reinterpret_cast<const b16x8*>(
                        su_sh + rowb + f * 640 + coff);
                GLDS(src, dst);                 // prefetch tap it2+2, first half
                BAR();
                WAIT_LGKM0(); SCHEDB();
                __builtin_amdgcn_s_setprio(1);
                #pragma unroll
                for (int f = 0; f < 4; ++f)
                    #pragma unroll
                    for (int fr = 0; fr < 4; ++fr)
                        acc[f][fr] = __builtin_amdgcn_mfma_f32_16x16x32_bf16(
                            afA[f], bfr[fr], acc[f][fr], 0, 0, 0);
                __builtin_amdgcn_s_setprio(0);
                BAR();

                // ================= phase B =================
                b16x8 afB[4];
                #pragma unroll
                for (int f = 0; f < 4; ++f)
                    afB[f] = *reinterpret_cast<const b16x8*>(
                        su_sh + rowb + (f + 4) * 640 + coff);
                GLDS(src + 1024, dst + 1024);   // prefetch tap it2+2, second half
                WAIT_VM2();                      // retire tap it2+1's loads, keep it2+2's in flight
                BAR();
                WAIT_LGKM0(); SCHEDB();
                __builtin_amdgcn_s_setprio(1);
                #pragma unroll
                for (int f = 0; f < 4; ++f)
                    #pragma unroll
                    for (int fr = 0; fr < 4; ++fr)
                        acc[f + 4][fr] = __builtin_amdgcn_mfma_f32_16x16x32_bf16(
                            afB[f], bfr[fr], acc[f + 4][fr], 0, 0, 0);
                __builtin_amdgcn_s_setprio(0);
                BAR();

                bufR = (bufR == 2) ? 0 : bufR + 1;
                bufW = (bufW == 2) ? 0 : bufW + 1;
            }
        }
        if (half == 0) {        // stage u half 1 (serial, once)
            __syncthreads();
            stage_u(1);
            __syncthreads();
        }
    }

    // ---------------- epilogue: bias + r-scale + squash + transposed store ----
    float bsv[4];
    #pragma unroll
    for (int fr = 0; fr < 4; ++fr) bsv[fr] = wsb[obase + fr * 16 + col];

    const int xg = lane >> 4;   // x-group in C layout
    #pragma unroll
    for (int f = 0; f < 8; ++f) {
        int h = ty0 + ybase + f;
        int rows = min(h + 2, 127) - max(h - 2, 0) + 1;
        #pragma unroll
        for (int p = 0; p < 2; ++p) {
            int oc = wn * 2 + p;
            float pv0[4], pv1[4], ss[4];
            #pragma unroll
            for (int r = 0; r < 4; ++r) {
                int w = tx0 + xg * 4 + r;
                int colsv = min(w + 2, 127) - max(w - 2, 0) + 1;
                float rs = 1.0f / (8.0f * (float)(rows * colsv));
                float p0 = (acc[f][2 * p][r] + bsv[2 * p]) * rs;
                float p1 = (acc[f][2 * p + 1][r] + bsv[2 * p + 1]) * rs;
                pv0[r] = p0; pv1[r] = p1;
                ss[r] = p0 * p0 + p1 * p1;
            }
            #pragma unroll
            for (int r = 0; r < 4; ++r) {
                float s = ss[r];
                s += __shfl_xor(s, 1);
                s += __shfl_xor(s, 2);
                s += __shfl_xor(s, 4);
                s += __shfl_xor(s, 8);
                float scale = s / ((1.0f + s) * sqrtf(s + 1e-9f));
                int w = tx0 + xg * 4 + r;
                size_t base0 = ((size_t)((b * 8 + oc) * 32) + col) * 16384
                               + (size_t)h * 128 + w;
                out[base0] = pv0[r] * scale;
                out[base0 + (size_t)16 * 16384] = pv1[r] * scale;
            }
        }
    }
}

extern "C" void kernel_launch(void* const* d_in, const int* in_sizes, int n_in,
                              void* d_out, int out_size, void* d_ws, size_t ws_size,
                              hipStream_t stream) {
    const float* u    = (const float*)d_in[0];
    const float* Wt   = (const float*)d_in[1];
    const float* bias = (const float*)d_in[2];
    unsigned short* wsw = (unsigned short*)d_ws;
    float* wsb = (float*)((char*)d_ws + 819200);

    repack_w<<<1601, 256, 0, stream>>>(Wt, bias, wsw, wsb);
    caps_mfma<<<dim3(64, 4), 512, 0, stream>>>(u, wsw, wsb, (float*)d_out);
}

// Round 4
// 78.242 us; speedup vs baseline: 12.9705x; 1.0008x over previous
//
#include <hip/hip_runtime.h>
#include <math.h>

typedef __attribute__((ext_vector_type(8))) __bf16 b16x8;
typedef __attribute__((ext_vector_type(4))) float f32x4;

#define GLDS(gp, lp) __builtin_amdgcn_global_load_lds(                         \
    (const __attribute__((address_space(1))) unsigned int*)(gp),               \
    (__attribute__((address_space(3))) unsigned int*)(lp), 16, 0, 0)

#define WAIT_VM4()   asm volatile("s_waitcnt vmcnt(4)" ::: "memory")
#define BAR()        __builtin_amdgcn_s_barrier()

__device__ __forceinline__ unsigned short f2bf(float x) {
    unsigned int v = __float_as_uint(x);
    v += 0x7fffu + ((v >> 16) & 1u);
    return (unsigned short)(v >> 16);
}

// ---------------- repack kernel ----------------
// ws layout: [0, 819200): weights bf16
//   idx = ((tap*2 + ks)*256 + o)*32 + cgp*8 + j     (ushort index, tap=kh*5+kw)
//   stored cin = ks*32 + (cgp ^ ((o>>1)&3))*8 + j   (XOR swizzle for LDS banks)
// [819200, 820224): bias_sum fp32 [256]
__global__ __launch_bounds__(256) void repack_w(
    const float* __restrict__ Wt, const float* __restrict__ bias,
    unsigned short* __restrict__ wsw, float* __restrict__ wsb) {
    int idx = blockIdx.x * 256 + threadIdx.x;
    if (idx < 409600) {
        int j    = idx & 7;
        int cgp  = (idx >> 3) & 3;
        int o    = (idx >> 5) & 255;
        int ks   = (idx >> 13) & 1;
        int tap  = idx >> 14;          // 0..24
        int cg   = cgp ^ ((o >> 1) & 3);
        int cin  = ks * 32 + cg * 8 + j;
        int ic = cin >> 4, id = cin & 15;
        float w = Wt[((size_t)(ic * 256 + o) * 16 + id) * 25 + tap];
        wsw[idx] = f2bf(w);
    } else if (idx < 409856) {
        int o = idx - 409600;
        float s = 0.f;
        for (int ic = 0; ic < 4; ++ic) s += bias[ic * 256 + o];
        wsb[o] = s;
    }
}

// ---------------- main kernel ----------------
// Block: one 16x16 spatial tile x all 256 outputs, 512 threads (8 waves).
// Wave tile: 128 pixels x 64 outputs = 8 pixfrags x 4 ofrags (16x16x32 MFMA).
// K loop: 25 taps, K=64 per tap (both cin-planes). Full u halo (64 cin) staged
// once in prologue. Weights triple-buffered (prefetch depth 2, 32KB/tap) via
// global_load_lds; ONE s_barrier per tap + counted vmcnt(4) (never 0 in loop).
__global__ __launch_bounds__(512, 2) void caps_mfma(
    const float* __restrict__ u, const unsigned short* __restrict__ wsw,
    const float* __restrict__ wsb, float* __restrict__ out) {

    __shared__ __align__(16) unsigned short su_sh[25600];       // 2 planes x [hy20][hx20][cgp4][j8]
    __shared__ __align__(16) unsigned short sw_sh[3][16384];    // 3 x [ks2][o256][cgp4][j8]

    const int tid  = threadIdx.x;
    const int lane = tid & 63;
    const int wid  = tid >> 6;
    const int wm   = wid >> 2;      // 0..1  pixel-row-group
    const int wn   = wid & 3;       // 0..3  output-col-group
    const int col  = lane & 15;
    const int cg   = lane >> 4;     // 0..3  cin-group (and x-group in C layout)
    const int ybase = wm * 8;
    const int obase = wn * 64;

    const int bx  = blockIdx.x;     // 0..63
    const int b   = blockIdx.y;     // 0..3
    const int ty0 = (bx >> 3) * 16;
    const int tx0 = (bx & 7) * 16;

    // B-frag element offsets (ushorts) within one weight plane
    int b_elem[4];
    #pragma unroll
    for (int fr = 0; fr < 4; ++fr) {
        int o = obase + fr * 16 + col;
        int cgp = cg ^ ((o >> 1) & 3);
        b_elem[fr] = o * 32 + cgp * 8;
    }

    // A-frag column offsets per kw (ushort index within a row cell, per plane)
    int coffs[5];
    #pragma unroll
    for (int kw = 0; kw < 5; ++kw) {
        int hx = col + kw;
        coffs[kw] = hx * 32 + ((cg ^ ((hx >> 1) & 3)) * 8);
    }

    f32x4 acc[8][4];
    #pragma unroll
    for (int f = 0; f < 8; ++f)
        #pragma unroll
        for (int fr = 0; fr < 4; ++fr) acc[f][fr] = (f32x4)0.f;

    auto stage_u = [&](int half) {
        const float* up = u + ((size_t)b * 64 + half * 32) * 16384;
        unsigned short* dstp = su_sh + half * 12800;
        #pragma unroll 1
        for (int i = tid; i < 12800; i += 512) {
            int c = i / 400;                    // cin local 0..31
            int s = i - c * 400;
            int hy = s / 20, hx = s - hy * 20;  // halo coords 0..19
            int gy = ty0 - 2 + hy, gx = tx0 - 2 + hx;
            float v = 0.f;
            if ((unsigned)gy < 128u && (unsigned)gx < 128u)
                v = up[(size_t)c * 16384 + gy * 128 + gx];
            int cgp = (c >> 3) ^ ((hx >> 1) & 3);
            dstp[(hy * 20 + hx) * 32 + cgp * 8 + (c & 7)] = f2bf(v);
        }
    };

    const char* wbase = ((const char*)wsw) + wid * 4096 + lane * 16;

    auto stage_w = [&](int tap, int bufI) {
        const char* src = wbase + (size_t)tap * 32768;
        char* dst = ((char*)sw_sh) + bufI * 32768 + wid * 4096;   // wave-uniform dest
        GLDS(src,        dst);
        GLDS(src + 1024, dst + 1024);
        GLDS(src + 2048, dst + 2048);
        GLDS(src + 3072, dst + 3072);
    };

    // prologue: stage full u halo (both planes) and weight taps 0,1
    stage_u(0);
    stage_u(1);
    stage_w(0, 0);
    stage_w(1, 1);
    __syncthreads();

    int bufR = 0, bufW = 2;
    #pragma unroll 1
    for (int kh = 0; kh < 5; ++kh) {
        #pragma unroll
        for (int kw = 0; kw < 5; ++kw) {
            const int t  = kh * 5 + kw;
            const int tn = (t + 2 > 24) ? 24 : t + 2;   // clamped prefetch src
            const int coff = coffs[kw];

            BAR();
            const unsigned short* swb = sw_sh[bufR];
            b16x8 bf0[4], bf1[4];
            #pragma unroll
            for (int fr = 0; fr < 4; ++fr) {
                bf0[fr] = *reinterpret_cast<const b16x8*>(swb + b_elem[fr]);
                bf1[fr] = *reinterpret_cast<const b16x8*>(swb + 8192 + b_elem[fr]);
            }
            b16x8 a0[8], a1[8];
            #pragma unroll
            for (int f = 0; f < 8; ++f) {
                int rb = (ybase + kh + f) * 640 + coff;
                a0[f] = *reinterpret_cast<const b16x8*>(su_sh + rb);
                a1[f] = *reinterpret_cast<const b16x8*>(su_sh + 12800 + rb);
            }
            stage_w(tn, bufW);                 // prefetch tap t+2

            __builtin_amdgcn_s_setprio(1);
            #pragma unroll
            for (int f = 0; f < 8; ++f)
                #pragma unroll
                for (int fr = 0; fr < 4; ++fr)
                    acc[f][fr] = __builtin_amdgcn_mfma_f32_16x16x32_bf16(
                        a0[f], bf0[fr], acc[f][fr], 0, 0, 0);
            #pragma unroll
            for (int f = 0; f < 8; ++f)
                #pragma unroll
                for (int fr = 0; fr < 4; ++fr)
                    acc[f][fr] = __builtin_amdgcn_mfma_f32_16x16x32_bf16(
                        a1[f], bf1[fr], acc[f][fr], 0, 0, 0);
            __builtin_amdgcn_s_setprio(0);

            WAIT_VM4();                        // tap t+1's 4 loads landed; t+2's stay in flight
            bufR = (bufR == 2) ? 0 : bufR + 1;
            bufW = (bufW == 2) ? 0 : bufW + 1;
        }
    }

    // ---------------- epilogue: bias + r-scale + squash + transposed store ----
    float bsv[4];
    #pragma unroll
    for (int fr = 0; fr < 4; ++fr) bsv[fr] = wsb[obase + fr * 16 + col];

    const int xg = lane >> 4;   // x-group in C layout
    #pragma unroll
    for (int f = 0; f < 8; ++f) {
        int h = ty0 + ybase + f;
        int rows = min(h + 2, 127) - max(h - 2, 0) + 1;
        #pragma unroll
        for (int p = 0; p < 2; ++p) {
            int oc = wn * 2 + p;
            float pv0[4], pv1[4], ss[4];
            #pragma unroll
            for (int r = 0; r < 4; ++r) {
                int w = tx0 + xg * 4 + r;
                int colsv = min(w + 2, 127) - max(w - 2, 0) + 1;
                float rs = 1.0f / (8.0f * (float)(rows * colsv));
                float p0 = (acc[f][2 * p][r] + bsv[2 * p]) * rs;
                float p1 = (acc[f][2 * p + 1][r] + bsv[2 * p + 1]) * rs;
                pv0[r] = p0; pv1[r] = p1;
                ss[r] = p0 * p0 + p1 * p1;
            }
            #pragma unroll
            for (int r = 0; r < 4; ++r) {
                float s = ss[r];
                s += __shfl_xor(s, 1);
                s += __shfl_xor(s, 2);
                s += __shfl_xor(s, 4);
                s += __shfl_xor(s, 8);
                float scale = s / ((1.0f + s) * sqrtf(s + 1e-9f));
                int w = tx0 + xg * 4 + r;
                size_t base0 = ((size_t)((b * 8 + oc) * 32) + col) * 16384
                               + (size_t)h * 128 + w;
                out[base0] = pv0[r] * scale;
                out[base0 + (size_t)16 * 16384] = pv1[r] * scale;
            }
        }
    }
}

extern "C" void kernel_launch(void* const* d_in, const int* in_sizes, int n_in,
                              void* d_out, int out_size, void* d_ws, size_t ws_size,
                              hipStream_t stream) {
    const float* u    = (const float*)d_in[0];
    const float* Wt   = (const float*)d_in[1];
    const float* bias = (const float*)d_in[2];
    unsigned short* wsw = (unsigned short*)d_ws;
    float* wsb = (float*)((char*)d_ws + 819200);

    repack_w<<<1601, 256, 0, stream>>>(Wt, bias, wsw, wsb);
    caps_mfma<<<dim3(64, 4), 512, 0, stream>>>(u, wsw, wsb, (float*)d_out);
}

// Round 5
// 76.243 us; speedup vs baseline: 13.3107x; 1.0262x over previous
//
#include <hip/hip_runtime.h>
#include <math.h>

typedef __attribute__((ext_vector_type(8))) __bf16 b16x8;
typedef __attribute__((ext_vector_type(4))) float f32x4;

#define GLDS(gp, lp) __builtin_amdgcn_global_load_lds(                         \
    (const __attribute__((address_space(1))) unsigned int*)(gp),               \
    (__attribute__((address_space(3))) unsigned int*)(lp), 16, 0, 0)

#define WAIT_VM4()   asm volatile("s_waitcnt vmcnt(4)" ::: "memory")
#define WAIT_VM0()   asm volatile("s_waitcnt vmcnt(0)" ::: "memory")
#define BAR()        __builtin_amdgcn_s_barrier()

__device__ __forceinline__ unsigned short f2bf(float x) {
    unsigned int v = __float_as_uint(x);
    v += 0x7fffu + ((v >> 16) & 1u);
    return (unsigned short)(v >> 16);
}

// ---------------- repack kernel ----------------
// ws layout: [0, 819200): weights bf16, stored in MAIN-LOOP slot order:
//   slot s = kw*5 + kh   corresponds to conv tap = kh*5 + kw
//   idx = ((s*2 + ks)*256 + o)*32 + cgp*8 + j       (ushort index)
//   stored cin = ks*32 + (cgp ^ ((o>>1)&3))*8 + j   (XOR swizzle for LDS banks)
// [819200, 820224): bias_sum fp32 [256]
__global__ __launch_bounds__(256) void repack_w(
    const float* __restrict__ Wt, const float* __restrict__ bias,
    unsigned short* __restrict__ wsw, float* __restrict__ wsb) {
    int idx = blockIdx.x * 256 + threadIdx.x;
    if (idx < 409600) {
        int j    = idx & 7;
        int cgp  = (idx >> 3) & 3;
        int o    = (idx >> 5) & 255;
        int ks   = (idx >> 13) & 1;
        int s    = idx >> 14;          // slot 0..24
        int kwv  = s / 5;
        int khv  = s - kwv * 5;
        int tap  = khv * 5 + kwv;      // conv tap for this slot
        int cg   = cgp ^ ((o >> 1) & 3);
        int cin  = ks * 32 + cg * 8 + j;
        int ic = cin >> 4, id = cin & 15;
        float w = Wt[((size_t)(ic * 256 + o) * 16 + id) * 25 + tap];
        wsw[idx] = f2bf(w);
    } else if (idx < 409856) {
        int o = idx - 409600;
        float s = 0.f;
        for (int ic = 0; ic < 4; ++ic) s += bias[ic * 256 + o];
        wsb[o] = s;
    }
}

// ---------------- main kernel ----------------
// Block: one 16x16 spatial tile x all 256 outputs, 512 threads (8 waves).
// Wave tile: 128 pixels x 64 outputs = 8 pixfrags x 4 ofrags (16x16x32 MFMA).
// Loop: kw outer, kh inner (slot s = kw*5+kh walks weights sequentially).
// A-fragments held in a 12-row register window per cin-plane: per kw preload
// 8 rows/plane, each kh step reads only 2 new rows (A LDS traffic /3.3).
// Weights triple-buffered (depth-2 prefetch) via global_load_lds; one
// s_barrier per tap + counted vmcnt(4) (never 0 in the main loop).
__global__ __launch_bounds__(512, 2) void caps_mfma(
    const float* __restrict__ u, const unsigned short* __restrict__ wsw,
    const float* __restrict__ wsb, float* __restrict__ out) {

    __shared__ __align__(16) unsigned short su_sh[25600];       // 2 planes x [hy20][hx20][cgp4][j8]
    __shared__ __align__(16) unsigned short sw_sh[3][16384];    // 3 x [ks2][o256][cgp4][j8]

    const int tid  = threadIdx.x;
    const int lane = tid & 63;
    const int wid  = tid >> 6;
    const int wm   = wid >> 2;      // 0..1  pixel-row-group
    const int wn   = wid & 3;       // 0..3  output-col-group
    const int col  = lane & 15;
    const int cg   = lane >> 4;     // 0..3  cin-group (and x-group in C layout)
    const int ybase = wm * 8;
    const int obase = wn * 64;

    const int bx  = blockIdx.x;     // 0..63
    const int b   = blockIdx.y;     // 0..3
    const int ty0 = (bx >> 3) * 16;
    const int tx0 = (bx & 7) * 16;

    // B-frag element offsets (ushorts) within one weight plane
    int b_elem[4];
    #pragma unroll
    for (int fr = 0; fr < 4; ++fr) {
        int o = obase + fr * 16 + col;
        int cgp = cg ^ ((o >> 1) & 3);
        b_elem[fr] = o * 32 + cgp * 8;
    }

    f32x4 acc[8][4];
    #pragma unroll
    for (int f = 0; f < 8; ++f)
        #pragma unroll
        for (int fr = 0; fr < 4; ++fr) acc[f][fr] = (f32x4)0.f;

    auto stage_u = [&](int half) {
        const float* up = u + ((size_t)b * 64 + half * 32) * 16384;
        unsigned short* dstp = su_sh + half * 12800;
        #pragma unroll 1
        for (int i = tid; i < 12800; i += 512) {
            int c = i / 400;                    // cin local 0..31
            int s = i - c * 400;
            int hy = s / 20, hx = s - hy * 20;  // halo coords 0..19
            int gy = ty0 - 2 + hy, gx = tx0 - 2 + hx;
            float v = 0.f;
            if ((unsigned)gy < 128u && (unsigned)gx < 128u)
                v = up[(size_t)c * 16384 + gy * 128 + gx];
            int cgp = (c >> 3) ^ ((hx >> 1) & 3);
            dstp[(hy * 20 + hx) * 32 + cgp * 8 + (c & 7)] = f2bf(v);
        }
    };

    const char* wbase = ((const char*)wsw) + wid * 4096 + lane * 16;

    auto stage_w = [&](int slot, int bufI) {
        const char* src = wbase + (size_t)slot * 32768;
        char* dst = ((char*)sw_sh) + bufI * 32768 + wid * 4096;   // wave-uniform dest
        GLDS(src,        dst);
        GLDS(src + 1024, dst + 1024);
        GLDS(src + 2048, dst + 2048);
        GLDS(src + 3072, dst + 3072);
    };

    // prologue: stage full u halo (both planes) and weight slots 0,1
    stage_u(0);
    stage_u(1);
    stage_w(0, 0);
    stage_w(1, 1);
    __syncthreads();

    int bufR = 0, bufW = 2;
    #pragma unroll 1
    for (int kw = 0; kw < 5; ++kw) {
        const int hx   = col + kw;
        const int coff = hx * 32 + ((cg ^ ((hx >> 1) & 3)) * 8);
        const unsigned short* ab0 = su_sh + ybase * 640 + coff;
        const unsigned short* ab1 = ab0 + 12800;

        // preload A-window rows 0..7 (both planes) — su is stable, no barrier needed
        b16x8 aw0[12], aw1[12];
        #pragma unroll
        for (int f = 0; f < 8; ++f) {
            aw0[f] = *reinterpret_cast<const b16x8*>(ab0 + f * 640);
            aw1[f] = *reinterpret_cast<const b16x8*>(ab1 + f * 640);
        }

        #pragma unroll
        for (int kh = 0; kh < 5; ++kh) {
            const int s  = kw * 5 + kh;
            const int sp = (s + 2 > 24) ? 24 : s + 2;   // clamped prefetch slot

            BAR();                           // sw_sh[bufR] fully landed (all waves)
            const unsigned short* swb = sw_sh[bufR];
            b16x8 bf0[4];
            #pragma unroll
            for (int fr = 0; fr < 4; ++fr)
                bf0[fr] = *reinterpret_cast<const b16x8*>(swb + b_elem[fr]);
            stage_w(sp, bufW);               // prefetch slot s+2

            __builtin_amdgcn_s_setprio(1);
            // cluster 0: plane 0, f=0..3
            #pragma unroll
            for (int f = 0; f < 4; ++f)
                #pragma unroll
                for (int fr = 0; fr < 4; ++fr)
                    acc[f][fr] = __builtin_amdgcn_mfma_f32_16x16x32_bf16(
                        aw0[kh + f], bf0[fr], acc[f][fr], 0, 0, 0);
            b16x8 bf1[4];
            #pragma unroll
            for (int fr = 0; fr < 4; ++fr)
                bf1[fr] = *reinterpret_cast<const b16x8*>(swb + 8192 + b_elem[fr]);
            // cluster 1: plane 0, f=4..7
            #pragma unroll
            for (int f = 4; f < 8; ++f)
                #pragma unroll
                for (int fr = 0; fr < 4; ++fr)
                    acc[f][fr] = __builtin_amdgcn_mfma_f32_16x16x32_bf16(
                        aw0[kh + f], bf0[fr], acc[f][fr], 0, 0, 0);
            // extend window for next kh (2 reads; hidden under clusters 2-3)
            if (kh < 4) {
                aw0[kh + 8] = *reinterpret_cast<const b16x8*>(ab0 + (kh + 8) * 640);
                aw1[kh + 8] = *reinterpret_cast<const b16x8*>(ab1 + (kh + 8) * 640);
            }
            // cluster 2: plane 1, f=0..3
            #pragma unroll
            for (int f = 0; f < 4; ++f)
                #pragma unroll
                for (int fr = 0; fr < 4; ++fr)
                    acc[f][fr] = __builtin_amdgcn_mfma_f32_16x16x32_bf16(
                        aw1[kh + f], bf1[fr], acc[f][fr], 0, 0, 0);
            // cluster 3: plane 1, f=4..7
            #pragma unroll
            for (int f = 4; f < 8; ++f)
                #pragma unroll
                for (int fr = 0; fr < 4; ++fr)
                    acc[f][fr] = __builtin_amdgcn_mfma_f32_16x16x32_bf16(
                        aw1[kh + f], bf1[fr], acc[f][fr], 0, 0, 0);
            __builtin_amdgcn_s_setprio(0);

            WAIT_VM4();                      // slot s+1's 4 loads landed; s+2's in flight
            bufR = (bufR == 2) ? 0 : bufR + 1;
            bufW = (bufW == 2) ? 0 : bufW + 1;
        }
    }
    WAIT_VM0();   // drain trailing GLDS before kernel end (LDS re-use safety)

    // ---------------- epilogue: bias + r-scale + squash + float4 store ----
    float bsv[4];
    #pragma unroll
    for (int fr = 0; fr < 4; ++fr) bsv[fr] = wsb[obase + fr * 16 + col];

    const int xg = lane >> 4;   // x-group in C layout
    #pragma unroll
    for (int f = 0; f < 8; ++f) {
        int h = ty0 + ybase + f;
        int rows = min(h + 2, 127) - max(h - 2, 0) + 1;
        #pragma unroll
        for (int p = 0; p < 2; ++p) {
            int oc = wn * 2 + p;
            float o0[4], o1[4], ss[4];
            #pragma unroll
            for (int r = 0; r < 4; ++r) {
                int w = tx0 + xg * 4 + r;
                int colsv = min(w + 2, 127) - max(w - 2, 0) + 1;
                float rs = 1.0f / (8.0f * (float)(rows * colsv));
                float p0 = (acc[f][2 * p][r] + bsv[2 * p]) * rs;
                float p1 = (acc[f][2 * p + 1][r] + bsv[2 * p + 1]) * rs;
                o0[r] = p0; o1[r] = p1;
                ss[r] = p0 * p0 + p1 * p1;
            }
            #pragma unroll
            for (int r = 0; r < 4; ++r) {
                float sv = ss[r];
                sv += __shfl_xor(sv, 1);
                sv += __shfl_xor(sv, 2);
                sv += __shfl_xor(sv, 4);
                sv += __shfl_xor(sv, 8);
                float scale = sv / ((1.0f + sv) * sqrtf(sv + 1e-9f));
                o0[r] *= scale; o1[r] *= scale;
            }
            size_t base = ((size_t)((b * 8 + oc) * 32) + col) * 16384
                          + (size_t)h * 128 + tx0 + xg * 4;
            float4 v0 = make_float4(o0[0], o0[1], o0[2], o0[3]);
            float4 v1 = make_float4(o1[0], o1[1], o1[2], o1[3]);
            *reinterpret_cast<float4*>(out + base) = v0;
            *reinterpret_cast<float4*>(out + base + (size_t)16 * 16384) = v1;
        }
    }
}

extern "C" void kernel_launch(void* const* d_in, const int* in_sizes, int n_in,
                              void* d_out, int out_size, void* d_ws, size_t ws_size,
                              hipStream_t stream) {
    const float* u    = (const float*)d_in[0];
    const float* Wt   = (const float*)d_in[1];
    const float* bias = (const float*)d_in[2];
    unsigned short* wsw = (unsigned short*)d_ws;
    float* wsb = (float*)((char*)d_ws + 819200);

    repack_w<<<1601, 256, 0, stream>>>(Wt, bias, wsw, wsb);
    caps_mfma<<<dim3(64, 4), 512, 0, stream>>>(u, wsw, wsb, (float*)d_out);
}